// Round 7
// baseline (180.361 us; speedup 1.0000x reference)
//
#include <hip/hip_runtime.h>

#define NBLOCK 64
#define TPB 256
#define ROWU 36   // u32 stride per voice row: 32 f16-pairs + inv @ [32] + pad (144 B: 16B-aligned)

typedef __fp16 half2_t __attribute__((ext_vector_type(2)));   // matches cvt_pkrtz return
union PK { half2_t h2; unsigned int u; };

// sin(x) for |x| <~ 200, abs error ~1e-7.
// Cody-Waite pi/2 reduction (2 fmas) + cephes polys on [-pi/4, pi/4].
__device__ __forceinline__ float fast_sinf(float x) {
    float kf = rintf(x * 0.63661977236758134f);   // round(x * 2/pi)
    int   q  = (int)kf;
    float r = fmaf(kf, -1.5707963705062866f, x);  // x - k*HI (fma-exact product)
    r = fmaf(kf, 4.3711390001862171e-8f, r);      // - k*LO
    float z = r * r;
    float s = fmaf(z, fmaf(z, -1.9515295891e-4f, 8.3321608736e-3f), -1.6666654611e-1f);
    float sinr = fmaf(z * r, s, r);
    float c = fmaf(z, fmaf(z, 2.4433157118e-5f, -1.3887316255e-3f), 4.1666645683e-2f);
    float cosr = fmaf(z, fmaf(z, c, -0.5f), 1.0f);
    float res = (q & 1) ? cosr : sinr;
    return (q & 2) ? -res : res;
}

// Exact floored fmod vs float32(2*pi), bit-matching numpy fp32 semantics.
__device__ __forceinline__ float mod_two_pi(float x) {
    const float Y = 6.2831853071795864769f;       // rounds to float32 2*pi
    float kf = floorf(__fdiv_rn(x, Y));
    float m = fmaf(-kf, Y, x);
    if (m < 0.0f)  { kf -= 1.0f; m = fmaf(-kf, Y, x); }
    if (m >= Y)    { kf += 1.0f; m = fmaf(-kf, Y, x); }
    return m;
}

// Round-6 structure (retry; r6 was a compile-type fix only):
//  - Recurrence, ss, inv, phase_end: exact f32 (unchanged numerics).
//  - Sample PAYLOAD packed to fp16 pairs in-register (cvt_pkrtz): register
//    state 64 f32 (was AGPR-spilled, ~120 regs total, 4 waves/SIMD) ->
//    32 u32 VGPRs (~70 total, 6-7 waves/SIMD). Kills all accvgpr moves and
//    the separate RMS-read/scale passes. absmax threshold 0.03125 >> the
//    ~8e-3 worst-case fp16 payload error (scaling stays f32 at the reader).
//  - Store path keeps the proven contiguous shape: per-wave private LDS
//    slab, 2 chunks x 32 voices; deposit 8x b128 (4 dw/bank floor), read
//    b64 transposed (4 dw/bank floor), each wave-store = 1 KB contiguous
//    (full 128B lines only -> write amp 1.0). No barriers (intra-wave
//    lgkmcnt ordering only). LDS 18432 B/block -> 8 blocks/CU.
__global__ __launch_bounds__(TPB, 6)
void fm_synth_kernel(const float* __restrict__ fm_params,
                     const float* __restrict__ f0_hz,
                     const float* __restrict__ phase_state,
                     float* __restrict__ out, int nv)
{
    __shared__ unsigned int lds[4 * 32 * ROWU];   // 4 waves x 32 rows x 36 u32 = 18432 B

    int tid  = threadIdx.x;
    int lane = tid & 63;
    int wv   = tid >> 6;
    int blockBase = blockIdx.x * TPB;
    int b   = blockBase + tid;
    int bc  = min(b, nv - 1);          // clamped compute index (grid may overshoot)
    bool live = (b < nv);

    // ---- loads -----------------------------------------------------------
    const float2* fm2 = (const float2*)fm_params;   // 6 floats/voice, 8B aligned
    float2 p01 = fm2[bc * 3 + 0];
    float2 p23 = fm2[bc * 3 + 1];
    float2 p45 = fm2[bc * 3 + 2];
    float  f0  = fmaxf(f0_hz[bc], 1.0f);
    float4 st  = ((const float4*)phase_state)[bc];

    // ---- params — exact fp32 op order matching the reference -------------
    const float TWO_PI = 6.2831853071795864769f;
    float r1  = __fadd_rn(0.25f, __fmul_rn(p01.y, 15.75f));
    float fb1 = __fmul_rn(p23.x, 0.95f);
    float d2  = __fmul_rn(p23.y, 10.0f);
    float r2  = __fadd_rn(0.25f, __fmul_rn(p45.x, 15.75f));
    float fb2 = __fmul_rn(p45.y, 0.95f);
    float inc1 = __fdiv_rn(__fmul_rn(__fmul_rn(TWO_PI, f0), r1), 16000.0f);
    float inc2 = __fdiv_rn(__fmul_rn(__fmul_rn(TWO_PI, f0), r2), 16000.0f);

    float start1 = st.x, start2 = st.y;
    float l1 = st.z, l2 = st.w;

    // ---- 64-step feedback FM recurrence; ss inline (same fp order as the
    //      old two-pass: t-ascending fma); samples packed to fp16 pairs ----
    unsigned int smph[32];
    float ss = 0.0f;
    float prev = 0.0f;
#pragma unroll
    for (int t = 0; t < NBLOCK; ++t) {
        float tf  = (float)t;
        float ph1 = tf * inc1 + start1;
        float ph2 = tf * inc2 + start2;
        float o1 = fast_sinf(ph1 + fb1 * l1);
        float o2 = fast_sinf(ph2 + d2 * o1 + fb2 * l2);
        l1 = o1;
        l2 = o2;
        ss = fmaf(o2, o2, ss);
        if (t & 1) {
            PK pk; pk.h2 = __builtin_amdgcn_cvt_pkrtz(prev, o2);
            smph[t >> 1] = pk.u;
        } else {
            prev = o2;
        }
    }
    float inv = 1.0f / sqrtf(ss * 0.015625f + 1e-5f);

    // ---- phase_end (exact f32; coalesced float4/thread; drains under the
    //      transpose) -------------------------------------------------------
    float x1 = __fadd_rn(start1, __fmul_rn(64.0f, inc1));
    float x2 = __fadd_rn(start2, __fmul_rn(64.0f, inc2));
    float4 pe;
    pe.x = mod_two_pi(x1);
    pe.y = mod_two_pi(x2);
    pe.z = l1;
    pe.w = l2;
    if (live)
        ((float4*)(out + (size_t)nv * NBLOCK))[b] = pe;

    // ---- audio store: per-wave slab, 2 chunks x 32 voices, no barriers ----
    float4* out4 = (float4*)out;
    unsigned int* slab = &lds[wv * (32 * ROWU)];
    int grp = lane >> 5;               // which chunk this lane's voice is in
    int row = lane & 31;               // row within chunk
#pragma unroll
    for (int c = 0; c < 2; ++c) {
        if (grp == c) {                // 32 lanes deposit whole packed rows
            unsigned int* slot = &slab[row * ROWU];
#pragma unroll
            for (int i = 0; i < 8; ++i) {
                uint4 w;
                w.x = smph[4 * i + 0];
                w.y = smph[4 * i + 1];
                w.z = smph[4 * i + 2];
                w.w = smph[4 * i + 3];
                *(uint4*)&slot[4 * i] = w;
            }
            slot[32] = __float_as_uint(inv);
        }
        // all 64 lanes: transposed read + dense 8 KB contiguous segment
        int vbase = blockBase + wv * 64 + c * 32;
        size_t gb4 = (size_t)vbase * 16;       // float4 units
#pragma unroll
        for (int j = 0; j < 8; ++j) {
            int f    = j * 64 + lane;          // 0..511: flat float4 idx in segment
            int voff = f >> 4;                 // voice within chunk (0..31)
            int p    = f & 15;                 // float4 within row (samples 4p..4p+3)
            const unsigned int* rp = &slab[voff * ROWU + 2 * p];
            unsigned int u0 = rp[0];
            unsigned int u1 = rp[1];           // merges to ds_read_b64 (8B-aligned)
            float vinv = __uint_as_float(slab[voff * ROWU + 32]);
            PK a; a.u = u0;
            PK q; q.u = u1;
            float4 val;
            val.x = (float)a.h2.x * vinv;
            val.y = (float)a.h2.y * vinv;
            val.z = (float)q.h2.x * vinv;
            val.w = (float)q.h2.y * vinv;
            if (vbase + voff < nv)
                out4[gb4 + f] = val;
        }
    }
}

extern "C" void kernel_launch(void* const* d_in, const int* in_sizes, int n_in,
                              void* d_out, int out_size, void* d_ws, size_t ws_size,
                              hipStream_t stream) {
    const float* fm_params   = (const float*)d_in[0];
    const float* f0_hz       = (const float*)d_in[1];
    const float* phase_state = (const float*)d_in[2];
    float* out = (float*)d_out;
    int nv = in_sizes[1];                      // f0_hz has one element per voice
    int grid = (nv + TPB - 1) / TPB;
    fm_synth_kernel<<<grid, TPB, 0, stream>>>(fm_params, f0_hz, phase_state, out, nv);
}

// Round 8
// 172.967 us; speedup vs baseline: 1.0427x; 1.0427x over previous
//
#include <hip/hip_runtime.h>

#define NBLOCK 64
#define TPB 256
#define ROWU 36   // u32 stride per voice row: 32 f16-pairs + inv @ [32] + pad (144 B: 16B-aligned)

typedef __fp16 half2_t __attribute__((ext_vector_type(2)));   // matches cvt_pkrtz return
union PK { half2_t h2; unsigned int u; };

// Hardware sine: v_sin_f32 computes sin(2*pi*x); v_fract makes the input
// range always valid. 3 instrs total (fma upstream) vs 18 for the poly.
__device__ __forceinline__ float sin_rev(float xrev) {
    return __builtin_amdgcn_sinf(__builtin_amdgcn_fractf(xrev));
}

// Exact floored fmod vs float32(2*pi), bit-matching numpy fp32 semantics.
__device__ __forceinline__ float mod_two_pi(float x) {
    const float Y = 6.2831853071795864769f;       // rounds to float32 2*pi
    float kf = floorf(__fdiv_rn(x, Y));
    float m = fmaf(-kf, Y, x);
    if (m < 0.0f)  { kf -= 1.0f; m = fmaf(-kf, Y, x); }
    if (m >= Y)    { kf += 1.0f; m = fmaf(-kf, Y, x); }
    return m;
}

// Round-8:
//  - Recurrence in REVOLUTION space with hardware v_sin_f32 (+fract): per
//    step ~11 VALU instrs vs ~42 with the poly. hw-sin err ~2^-20; feedback
//    amplification (x d2<=10, /(1-0.95)) worst ~4e-3 << 0.03125 threshold.
//  - Persistent state: 32 packed-fp16 smph + ~20 scalars -> fits 64 VGPR;
//    __launch_bounds__(256, 8) targets 8 waves/SIMD (512-reg file / 64).
//    This is the occupancy round 0-7 never had (4 waves/SIMD at 120 regs).
//  - phase_end: exact f32 radian math as before (computed pre-loop for
//    pe.x/y; l1,l2 appended post-loop).
//  - Store path unchanged from r7: per-wave private slab, 2 chunks x 32
//    voices, deposit b128 / transposed b64 reads / 1 KB contiguous
//    wave-stores (full 128B lines only), zero barriers. LDS 18432 B/block.
__global__ __launch_bounds__(TPB, 8)
void fm_synth_kernel(const float* __restrict__ fm_params,
                     const float* __restrict__ f0_hz,
                     const float* __restrict__ phase_state,
                     float* __restrict__ out, int nv)
{
    __shared__ unsigned int lds[4 * 32 * ROWU];   // 4 waves x 32 rows x 36 u32 = 18432 B

    int tid  = threadIdx.x;
    int lane = tid & 63;
    int wv   = tid >> 6;
    int blockBase = blockIdx.x * TPB;
    int b   = blockBase + tid;
    int bc  = min(b, nv - 1);          // clamped compute index (grid may overshoot)
    bool live = (b < nv);

    // ---- loads -----------------------------------------------------------
    const float2* fm2 = (const float2*)fm_params;   // 6 floats/voice, 8B aligned
    float2 p01 = fm2[bc * 3 + 0];
    float2 p23 = fm2[bc * 3 + 1];
    float2 p45 = fm2[bc * 3 + 2];
    float  f0  = fmaxf(f0_hz[bc], 1.0f);
    float4 st  = ((const float4*)phase_state)[bc];

    // ---- params — exact fp32 op order matching the reference -------------
    const float TWO_PI  = 6.2831853071795864769f;
    const float INV2PI  = 0.15915494309189533577f; // float32(1/(2*pi))
    float r1  = __fadd_rn(0.25f, __fmul_rn(p01.y, 15.75f));
    float fb1 = __fmul_rn(p23.x, 0.95f);
    float d2  = __fmul_rn(p23.y, 10.0f);
    float r2  = __fadd_rn(0.25f, __fmul_rn(p45.x, 15.75f));
    float fb2 = __fmul_rn(p45.y, 0.95f);
    float inc1 = __fdiv_rn(__fmul_rn(__fmul_rn(TWO_PI, f0), r1), 16000.0f);
    float inc2 = __fdiv_rn(__fmul_rn(__fmul_rn(TWO_PI, f0), r2), 16000.0f);

    float start1 = st.x, start2 = st.y;
    float l1 = st.z, l2 = st.w;

    // pe.x/pe.y now (exact radian math); frees inc/start radian regs early.
    float pex = mod_two_pi(__fadd_rn(start1, __fmul_rn(64.0f, inc1)));
    float pey = mod_two_pi(__fadd_rn(start2, __fmul_rn(64.0f, inc2)));

    // Revolution-space copies for the hw-sin loop.
    float inc1r   = inc1 * INV2PI;
    float inc2r   = inc2 * INV2PI;
    float start1r = start1 * INV2PI;
    float start2r = start2 * INV2PI;
    float fb1r    = fb1 * INV2PI;
    float fb2r    = fb2 * INV2PI;
    float d2r     = d2  * INV2PI;

    // ---- 64-step feedback FM recurrence (rev space, hw sin); ss inline;
    //      samples packed to fp16 pairs -----------------------------------
    unsigned int smph[32];
    float ss = 0.0f;
    float prev = 0.0f;
#pragma unroll
    for (int t = 0; t < NBLOCK; ++t) {
        float tf  = (float)t;
        float ph1 = fmaf(tf, inc1r, start1r);
        float ph2 = fmaf(tf, inc2r, start2r);
        float o1 = sin_rev(fmaf(fb1r, l1, ph1));
        float o2 = sin_rev(fmaf(d2r, o1, fmaf(fb2r, l2, ph2)));
        l1 = o1;
        l2 = o2;
        ss = fmaf(o2, o2, ss);
        if (t & 1) {
            PK pk; pk.h2 = __builtin_amdgcn_cvt_pkrtz(prev, o2);
            smph[t >> 1] = pk.u;
        } else {
            prev = o2;
        }
    }
    float inv = 1.0f / sqrtf(ss * 0.015625f + 1e-5f);

    // ---- phase_end store (coalesced float4/thread) ------------------------
    float4 pe;
    pe.x = pex;
    pe.y = pey;
    pe.z = l1;
    pe.w = l2;
    if (live)
        ((float4*)(out + (size_t)nv * NBLOCK))[b] = pe;

    // ---- audio store: per-wave slab, 2 chunks x 32 voices, no barriers ----
    float4* out4 = (float4*)out;
    unsigned int* slab = &lds[wv * (32 * ROWU)];
    int grp = lane >> 5;               // which chunk this lane's voice is in
    int row = lane & 31;               // row within chunk
#pragma unroll
    for (int c = 0; c < 2; ++c) {
        if (grp == c) {                // 32 lanes deposit whole packed rows
            unsigned int* slot = &slab[row * ROWU];
#pragma unroll
            for (int i = 0; i < 8; ++i) {
                uint4 w;
                w.x = smph[4 * i + 0];
                w.y = smph[4 * i + 1];
                w.z = smph[4 * i + 2];
                w.w = smph[4 * i + 3];
                *(uint4*)&slot[4 * i] = w;
            }
            slot[32] = __float_as_uint(inv);
        }
        // all 64 lanes: transposed read + dense 8 KB contiguous segment
        int vbase = blockBase + wv * 64 + c * 32;
        size_t gb4 = (size_t)vbase * 16;       // float4 units
#pragma unroll
        for (int j = 0; j < 8; ++j) {
            int f    = j * 64 + lane;          // 0..511: flat float4 idx in segment
            int voff = f >> 4;                 // voice within chunk (0..31)
            int p    = f & 15;                 // float4 within row (samples 4p..4p+3)
            const unsigned int* rp = &slab[voff * ROWU + 2 * p];
            unsigned int u0 = rp[0];
            unsigned int u1 = rp[1];           // merges to ds_read_b64 (8B-aligned)
            float vinv = __uint_as_float(slab[voff * ROWU + 32]);
            PK a; a.u = u0;
            PK q; q.u = u1;
            float4 val;
            val.x = (float)a.h2.x * vinv;
            val.y = (float)a.h2.y * vinv;
            val.z = (float)q.h2.x * vinv;
            val.w = (float)q.h2.y * vinv;
            if (vbase + voff < nv)
                out4[gb4 + f] = val;
        }
    }
}

extern "C" void kernel_launch(void* const* d_in, const int* in_sizes, int n_in,
                              void* d_out, int out_size, void* d_ws, size_t ws_size,
                              hipStream_t stream) {
    const float* fm_params   = (const float*)d_in[0];
    const float* f0_hz       = (const float*)d_in[1];
    const float* phase_state = (const float*)d_in[2];
    float* out = (float*)d_out;
    int nv = in_sizes[1];                      // f0_hz has one element per voice
    int grid = (nv + TPB - 1) / TPB;
    fm_synth_kernel<<<grid, TPB, 0, stream>>>(fm_params, f0_hz, phase_state, out, nv);
}

// Round 9
// 165.110 us; speedup vs baseline: 1.0924x; 1.0476x over previous
//
#include <hip/hip_runtime.h>

#define NBLOCK 64
#define TPB 256
#define GRID 512   // persistent: 2 blocks/CU; each block owns a contiguous voice range
#define ROWU 36    // u32 stride per voice row: 32 f16-pairs + inv @ [32] + pad (16B-aligned)

typedef __fp16 half2_t __attribute__((ext_vector_type(2)));   // matches cvt_pkrtz return
union PK { half2_t h2; unsigned int u; };

// Hardware sine: v_sin_f32 computes sin(2*pi*x); v_fract makes the input
// range always valid. ~3 instrs vs 18 for the poly (validated r8: passed).
__device__ __forceinline__ float sin_rev(float xrev) {
    return __builtin_amdgcn_sinf(__builtin_amdgcn_fractf(xrev));
}

// Exact floored fmod vs float32(2*pi), bit-matching numpy fp32 semantics.
__device__ __forceinline__ float mod_two_pi(float x) {
    const float Y = 6.2831853071795864769f;       // rounds to float32 2*pi
    float kf = floorf(__fdiv_rn(x, Y));
    float m = fmaf(-kf, Y, x);
    if (m < 0.0f)  { kf -= 1.0f; m = fmaf(-kf, Y, x); }
    if (m >= Y)    { kf += 1.0f; m = fmaf(-kf, Y, x); }
    return m;
}

// Round-9: HBM write-stream locality.
//   r0-r8 post-mortem: kernel pinned at ~85us with VALU 38%->~12% and HBM at
//   2.2 TB/s while the harness fill proves 6.8 TB/s on the same buffer. Both
//   pipes idle => DRAM row-buffer thrash from 2048-8192 concurrent 1KB write
//   bursts (every resident wave its own 16KB region). Fix: 512 persistent
//   blocks, block p writes voices [p*1024, p*1024+1024) over 4 chunks ->
//   512 sequentially-advancing 256KB streams with full page locality.
//   Compute (hw-sin, ~6-12us aggregate) hides under the store drain; slab
//   WAR across chunks is intra-wave (lgkmcnt), stores stay in flight.
__global__ __launch_bounds__(TPB, 2)
void fm_synth_kernel(const float* __restrict__ fm_params,
                     const float* __restrict__ f0_hz,
                     const float* __restrict__ phase_state,
                     float* __restrict__ out, int nv)
{
    __shared__ unsigned int lds[4 * 32 * ROWU];   // 4 waves x 32 rows x 36 u32 = 18432 B

    int tid  = threadIdx.x;
    int lane = tid & 63;
    int wv   = tid >> 6;
    float4* out4 = (float4*)out;
    float4* pe4  = (float4*)(out + (size_t)nv * NBLOCK);
    unsigned int* slab = &lds[wv * (32 * ROWU)];
    int grp = lane >> 5;               // which sub-chunk this lane deposits
    int row = lane & 31;               // row within sub-chunk

    // chunks per block so that block p covers a CONTIGUOUS voice range
    int nch = (nv + (int)gridDim.x * TPB - 1) / ((int)gridDim.x * TPB);
    int vstart = blockIdx.x * nch * TPB;

    for (int c = 0; c < nch; ++c) {
        int base = vstart + c * TPB;
        if (base >= nv) break;
        int  b    = base + tid;
        int  bc   = min(b, nv - 1);    // clamped compute index
        bool live = (b < nv);

        // ---- loads -------------------------------------------------------
        const float2* fm2 = (const float2*)fm_params;   // 6 floats/voice
        float2 p01 = fm2[bc * 3 + 0];
        float2 p23 = fm2[bc * 3 + 1];
        float2 p45 = fm2[bc * 3 + 2];
        float  f0  = fmaxf(f0_hz[bc], 1.0f);
        float4 st  = ((const float4*)phase_state)[bc];

        // ---- params — exact fp32 op order matching the reference ---------
        const float TWO_PI  = 6.2831853071795864769f;
        const float INV2PI  = 0.15915494309189533577f; // float32(1/(2*pi))
        float r1  = __fadd_rn(0.25f, __fmul_rn(p01.y, 15.75f));
        float fb1 = __fmul_rn(p23.x, 0.95f);
        float d2  = __fmul_rn(p23.y, 10.0f);
        float r2  = __fadd_rn(0.25f, __fmul_rn(p45.x, 15.75f));
        float fb2 = __fmul_rn(p45.y, 0.95f);
        float inc1 = __fdiv_rn(__fmul_rn(__fmul_rn(TWO_PI, f0), r1), 16000.0f);
        float inc2 = __fdiv_rn(__fmul_rn(__fmul_rn(TWO_PI, f0), r2), 16000.0f);

        float start1 = st.x, start2 = st.y;
        float l1 = st.z, l2 = st.w;

        // phase_end x/y now (exact radian math), frees regs early
        float pex = mod_two_pi(__fadd_rn(start1, __fmul_rn(64.0f, inc1)));
        float pey = mod_two_pi(__fadd_rn(start2, __fmul_rn(64.0f, inc2)));

        // revolution-space copies for the hw-sin loop
        float inc1r   = inc1 * INV2PI;
        float inc2r   = inc2 * INV2PI;
        float start1r = start1 * INV2PI;
        float start2r = start2 * INV2PI;
        float fb1r    = fb1 * INV2PI;
        float fb2r    = fb2 * INV2PI;
        float d2r     = d2  * INV2PI;

        // ---- 64-step recurrence (rev space, hw sin); ss inline; fp16 pack
        unsigned int smph[32];
        float ss = 0.0f;
        float prev = 0.0f;
#pragma unroll
        for (int t = 0; t < NBLOCK; ++t) {
            float tf  = (float)t;
            float ph1 = fmaf(tf, inc1r, start1r);
            float ph2 = fmaf(tf, inc2r, start2r);
            float o1 = sin_rev(fmaf(fb1r, l1, ph1));
            float o2 = sin_rev(fmaf(d2r, o1, fmaf(fb2r, l2, ph2)));
            l1 = o1;
            l2 = o2;
            ss = fmaf(o2, o2, ss);
            if (t & 1) {
                PK pk; pk.h2 = __builtin_amdgcn_cvt_pkrtz(prev, o2);
                smph[t >> 1] = pk.u;
            } else {
                prev = o2;
            }
        }
        float inv = 1.0f / sqrtf(ss * 0.015625f + 1e-5f);

        // ---- phase_end store (coalesced float4/thread) --------------------
        float4 pe;
        pe.x = pex;
        pe.y = pey;
        pe.z = l1;
        pe.w = l2;
        if (live) pe4[b] = pe;

        // ---- audio store: per-wave slab, 2 sub-chunks x 32 voices, no
        //      barriers. Slab WAR vs previous chunk's ds_reads is intra-wave
        //      program order (lgkmcnt); global stores stay in flight. -------
#pragma unroll
        for (int cc = 0; cc < 2; ++cc) {
            if (grp == cc) {           // 32 lanes deposit whole packed rows
                unsigned int* slot = &slab[row * ROWU];
#pragma unroll
                for (int i = 0; i < 8; ++i) {
                    uint4 w;
                    w.x = smph[4 * i + 0];
                    w.y = smph[4 * i + 1];
                    w.z = smph[4 * i + 2];
                    w.w = smph[4 * i + 3];
                    *(uint4*)&slot[4 * i] = w;
                }
                slot[32] = __float_as_uint(inv);
            }
            // all 64 lanes: transposed read + dense 8 KB contiguous segment
            int vbase = base + wv * 64 + cc * 32;
            size_t gb4 = (size_t)vbase * 16;       // float4 units
#pragma unroll
            for (int j = 0; j < 8; ++j) {
                int f    = j * 64 + lane;          // 0..511 flat float4 idx
                int voff = f >> 4;                 // voice within sub-chunk
                int p    = f & 15;                 // float4 within row
                const unsigned int* rp = &slab[voff * ROWU + 2 * p];
                unsigned int u0 = rp[0];
                unsigned int u1 = rp[1];           // ds_read_b64 (8B-aligned)
                float vinv = __uint_as_float(slab[voff * ROWU + 32]);
                PK a; a.u = u0;
                PK q; q.u = u1;
                float4 val;
                val.x = (float)a.h2.x * vinv;
                val.y = (float)a.h2.y * vinv;
                val.z = (float)q.h2.x * vinv;
                val.w = (float)q.h2.y * vinv;
                if (vbase + voff < nv)
                    out4[gb4 + f] = val;
            }
        }
    }
}

extern "C" void kernel_launch(void* const* d_in, const int* in_sizes, int n_in,
                              void* d_out, int out_size, void* d_ws, size_t ws_size,
                              hipStream_t stream) {
    const float* fm_params   = (const float*)d_in[0];
    const float* f0_hz       = (const float*)d_in[1];
    const float* phase_state = (const float*)d_in[2];
    float* out = (float*)d_out;
    int nv = in_sizes[1];                      // f0_hz has one element per voice
    int nblocks = (nv + TPB - 1) / TPB;
    int grid = nblocks < GRID ? nblocks : GRID;
    if (grid < 1) grid = 1;
    fm_synth_kernel<<<grid, TPB, 0, stream>>>(fm_params, f0_hz, phase_state, out, nv);
}

// Round 10
// 163.530 us; speedup vs baseline: 1.1029x; 1.0097x over previous
//
#include <hip/hip_runtime.h>

#define NBLOCK 64
#define TPB 256
#define GRID 512   // persistent: 2 blocks/CU; block p owns a contiguous 1024-voice range
#define ROWU 36    // u32 stride per voice row: 32 f16-pairs + inv @ [32] + pad (16B-aligned)

typedef __fp16 half2_t __attribute__((ext_vector_type(2)));   // matches cvt_pkrtz return
union PK { half2_t h2; unsigned int u; };

// Hardware sine: v_sin_f32 computes sin(2*pi*x); v_fract makes the input
// range always valid. Validated r8/r9 (passed, absmax unchanged).
__device__ __forceinline__ float sin_rev(float xrev) {
    return __builtin_amdgcn_sinf(__builtin_amdgcn_fractf(xrev));
}

// Exact floored fmod vs float32(2*pi), bit-matching numpy fp32 semantics.
__device__ __forceinline__ float mod_two_pi(float x) {
    const float Y = 6.2831853071795864769f;       // rounds to float32 2*pi
    float kf = floorf(__fdiv_rn(x, Y));
    float m = fmaf(-kf, Y, x);
    if (m < 0.0f)  { kf -= 1.0f; m = fmaf(-kf, Y, x); }
    if (m >= Y)    { kf += 1.0f; m = fmaf(-kf, Y, x); }
    return m;
}

// Round-10: break the ordered-vmcnt store->load serialization.
//   r9's loop issued loads(c) AFTER stores(c-1); consuming the loads forces
//   vmcnt(<=4), i.e. a FULL drain of the previous chunk's 17 stores before
//   each chunk's compute. Every wave alternated {drain-to-zero | compute} —
//   which is exactly the measured signature (VALU ~38% idle-in-antiphase
//   with HBM at 2 TB/s) and why barriers/occupancy/VALU/stream levers all
//   nulled: none changed queue ORDER.
//   Fix: prefetch chunk c+1's inputs BEFORE issuing chunk c's stores. The
//   inputs are then OLDEST in the vm queue; the compiler's waitcnt becomes
//   vmcnt(17) (the 17 newest = stores legitimately still in flight), so
//   stores drain under the NEXT chunk's compute with no forced drain point.
//   No __syncthreads anywhere; the if(grp==cc) branches place stores in
//   later basic blocks than the prefetch, so issue order is structural.
__global__ __launch_bounds__(TPB, 2)
void fm_synth_kernel(const float* __restrict__ fm_params,
                     const float* __restrict__ f0_hz,
                     const float* __restrict__ phase_state,
                     float* __restrict__ out, int nv)
{
    __shared__ unsigned int lds[4 * 32 * ROWU];   // 4 waves x 32 rows x 36 u32 = 18432 B

    int tid  = threadIdx.x;
    int lane = tid & 63;
    int wv   = tid >> 6;
    float4* out4 = (float4*)out;
    float4* pe4  = (float4*)(out + (size_t)nv * NBLOCK);
    const float2* fm2 = (const float2*)fm_params;
    const float4* ps4 = (const float4*)phase_state;
    unsigned int* slab = &lds[wv * (32 * ROWU)];
    int grp = lane >> 5;               // which sub-chunk this lane deposits
    int row = lane & 31;               // row within sub-chunk

    // block p covers a CONTIGUOUS voice range (sequential HBM stream, r9)
    int nch = (nv + (int)gridDim.x * TPB - 1) / ((int)gridDim.x * TPB);
    int vstart = blockIdx.x * nch * TPB;

    // ---- pipeline prologue: issue chunk-0 input loads ---------------------
    int bc0 = min(vstart + tid, nv - 1);
    float2 i01 = fm2[bc0 * 3 + 0];
    float2 i23 = fm2[bc0 * 3 + 1];
    float2 i45 = fm2[bc0 * 3 + 2];
    float  vf0 = f0_hz[bc0];
    float4 ist = ps4[bc0];

#pragma unroll 1
    for (int c = 0; c < nch; ++c) {
        int base = vstart + c * TPB;
        if (base >= nv) break;
        bool live = (base + tid) < nv;

        // ---- PREFETCH chunk c+1 inputs (issued before this chunk's
        //      stores -> they sit OLDEST in the vm queue; consuming them
        //      next iteration waits vmcnt(17), not vmcnt(0)) ---------------
        int bcn = min(vstart + (c + 1) * TPB + tid, nv - 1);
        float2 n01 = fm2[bcn * 3 + 0];
        float2 n23 = fm2[bcn * 3 + 1];
        float2 n45 = fm2[bcn * 3 + 2];
        float  nf0 = f0_hz[bcn];
        float4 nst = ps4[bcn];

        // ---- params — exact fp32 op order matching the reference ---------
        const float TWO_PI  = 6.2831853071795864769f;
        const float INV2PI  = 0.15915494309189533577f; // float32(1/(2*pi))
        float f0  = fmaxf(vf0, 1.0f);
        float r1  = __fadd_rn(0.25f, __fmul_rn(i01.y, 15.75f));
        float fb1 = __fmul_rn(i23.x, 0.95f);
        float d2  = __fmul_rn(i23.y, 10.0f);
        float r2  = __fadd_rn(0.25f, __fmul_rn(i45.x, 15.75f));
        float fb2 = __fmul_rn(i45.y, 0.95f);
        float inc1 = __fdiv_rn(__fmul_rn(__fmul_rn(TWO_PI, f0), r1), 16000.0f);
        float inc2 = __fdiv_rn(__fmul_rn(__fmul_rn(TWO_PI, f0), r2), 16000.0f);

        float start1 = ist.x, start2 = ist.y;
        float l1 = ist.z, l2 = ist.w;

        // phase_end x/y (exact radian math), frees regs early
        float pex = mod_two_pi(__fadd_rn(start1, __fmul_rn(64.0f, inc1)));
        float pey = mod_two_pi(__fadd_rn(start2, __fmul_rn(64.0f, inc2)));

        // revolution-space copies for the hw-sin loop
        float inc1r   = inc1 * INV2PI;
        float inc2r   = inc2 * INV2PI;
        float start1r = start1 * INV2PI;
        float start2r = start2 * INV2PI;
        float fb1r    = fb1 * INV2PI;
        float fb2r    = fb2 * INV2PI;
        float d2r     = d2  * INV2PI;

        // ---- 64-step recurrence (rev space, hw sin); ss inline; fp16 pack
        unsigned int smph[32];
        float ss = 0.0f;
        float prev = 0.0f;
#pragma unroll
        for (int t = 0; t < NBLOCK; ++t) {
            float tf  = (float)t;
            float ph1 = fmaf(tf, inc1r, start1r);
            float ph2 = fmaf(tf, inc2r, start2r);
            float o1 = sin_rev(fmaf(fb1r, l1, ph1));
            float o2 = sin_rev(fmaf(d2r, o1, fmaf(fb2r, l2, ph2)));
            l1 = o1;
            l2 = o2;
            ss = fmaf(o2, o2, ss);
            if (t & 1) {
                PK pk; pk.h2 = __builtin_amdgcn_cvt_pkrtz(prev, o2);
                smph[t >> 1] = pk.u;
            } else {
                prev = o2;
            }
        }
        float inv = 1.0f / sqrtf(ss * 0.015625f + 1e-5f);

        // ---- store phase (all stores issued AFTER the c+1 prefetch) -------
        float4 pe;
        pe.x = pex;
        pe.y = pey;
        pe.z = l1;
        pe.w = l2;
        if (live) pe4[base + tid] = pe;

        // audio: per-wave slab, 2 sub-chunks x 32 voices, no barriers.
        // Slab WAR vs previous chunk's ds_reads is intra-wave (lgkmcnt).
#pragma unroll
        for (int cc = 0; cc < 2; ++cc) {
            if (grp == cc) {           // 32 lanes deposit whole packed rows
                unsigned int* slot = &slab[row * ROWU];
#pragma unroll
                for (int i = 0; i < 8; ++i) {
                    uint4 w;
                    w.x = smph[4 * i + 0];
                    w.y = smph[4 * i + 1];
                    w.z = smph[4 * i + 2];
                    w.w = smph[4 * i + 3];
                    *(uint4*)&slot[4 * i] = w;
                }
                slot[32] = __float_as_uint(inv);
            }
            // all 64 lanes: transposed read + dense 8 KB contiguous segment
            int vbase = base + wv * 64 + cc * 32;
            size_t gb4 = (size_t)vbase * 16;       // float4 units
#pragma unroll
            for (int j = 0; j < 8; ++j) {
                int f    = j * 64 + lane;          // 0..511 flat float4 idx
                int voff = f >> 4;                 // voice within sub-chunk
                int p    = f & 15;                 // float4 within row
                const unsigned int* rp = &slab[voff * ROWU + 2 * p];
                unsigned int u0 = rp[0];
                unsigned int u1 = rp[1];           // ds_read_b64 (8B-aligned)
                float vinv = __uint_as_float(slab[voff * ROWU + 32]);
                PK a; a.u = u0;
                PK q; q.u = u1;
                float4 val;
                val.x = (float)a.h2.x * vinv;
                val.y = (float)a.h2.y * vinv;
                val.z = (float)q.h2.x * vinv;
                val.w = (float)q.h2.y * vinv;
                if (vbase + voff < nv)
                    out4[gb4 + f] = val;
            }
        }

        // ---- rotate pipeline registers -----------------------------------
        i01 = n01; i23 = n23; i45 = n45; vf0 = nf0; ist = nst;
    }
}

extern "C" void kernel_launch(void* const* d_in, const int* in_sizes, int n_in,
                              void* d_out, int out_size, void* d_ws, size_t ws_size,
                              hipStream_t stream) {
    const float* fm_params   = (const float*)d_in[0];
    const float* f0_hz       = (const float*)d_in[1];
    const float* phase_state = (const float*)d_in[2];
    float* out = (float*)d_out;
    int nv = in_sizes[1];                      // f0_hz has one element per voice
    int nblocks = (nv + TPB - 1) / TPB;
    int grid = nblocks < GRID ? nblocks : GRID;
    if (grid < 1) grid = 1;
    fm_synth_kernel<<<grid, TPB, 0, stream>>>(fm_params, f0_hz, phase_state, out, nv);
}